// Round 1
// baseline (744.822 us; speedup 1.0000x reference)
//
#include <hip/hip_runtime.h>
#include <hip/hip_bf16.h>
#include <cstdint>
#include <cstddef>

#define B_SZ 32768
#define H_SZ 896
#define K_SZ 2000
#define KPAD 2048
#define NPTR_COLS 256
#define NCAT 2304   /* KPAD + NPTR_COLS */
#define BM 128
#define BN 128
#define BK 32
#define TPS 6       /* tiles per split: 18 total tiles / 3 splits (balanced) */

typedef float floatx4 __attribute__((ext_vector_type(4)));
typedef __bf16 bf16x8 __attribute__((ext_vector_type(8)));

// Masked-logit sentinel: must stay FINITE after bf16 RNE rounding (harness
// compares through bf16; -3.4e38 rounds to -inf there and produced nan).
#define MASK_NEG 1.0e30f

__device__ inline unsigned short f2bf_rne(float x) {
  unsigned u = __builtin_bit_cast(unsigned, x);
  unsigned r = u + 0x7fffu + ((u >> 16) & 1u);
  return (unsigned short)(r >> 16);
}
__device__ inline float bf2f(unsigned short b) {
  unsigned u = ((unsigned)b) << 16;
  return __builtin_bit_cast(float, u);
}

typedef __attribute__((address_space(1))) void GV;
typedef __attribute__((address_space(3))) void LV;
__device__ inline void load_lds16(const void* gsrc, void* ldst) {
  __builtin_amdgcn_global_load_lds((GV*)gsrc, (LV*)ldst, 16, 0, 0);
}

// ---------------------------------------------------------------------------
// Kernel 1: build cat_hi/cat_lo bf16 split of [emb(2000); zeros(48); W(256)]
// rows x 896 (row-major, LINEAR layout), plus normE[k] = sum(emb[k]^2) fp32.
// ---------------------------------------------------------------------------
__global__ __launch_bounds__(256) void convert_kernel(
    const float* __restrict__ emb, const float* __restrict__ W,
    unsigned short* __restrict__ cat_hi, unsigned short* __restrict__ cat_lo,
    float* __restrict__ normE) {
  const int row = blockIdx.x;
  const int tid = threadIdx.x;
  const float* src = nullptr;
  bool zero = false;
  if (row < K_SZ)       src = emb + (size_t)row * H_SZ;
  else if (row < KPAD)  zero = true;
  else                  src = W + (size_t)(row - KPAD) * H_SZ;

  float ss = 0.f;
  for (int c = tid; c < H_SZ; c += 256) {
    float x = zero ? 0.f : src[c];
    unsigned short hb = f2bf_rne(x);
    float hf = bf2f(hb);
    unsigned short lb = f2bf_rne(x - hf);
    cat_hi[(size_t)row * H_SZ + c] = hb;
    cat_lo[(size_t)row * H_SZ + c] = lb;
    ss += x * x;
  }
  #pragma unroll
  for (int off = 32; off > 0; off >>= 1) ss += __shfl_down(ss, off);
  __shared__ float wsum[4];
  const int wave = tid >> 6, lane = tid & 63;
  if (lane == 0) wsum[wave] = ss;
  __syncthreads();
  if (tid == 0 && row < KPAD) normE[row] = wsum[0] + wsum[1] + wsum[2] + wsum[3];
}

// ---------------------------------------------------------------------------
// Kernel 1b: precompute z -> zhi/zlo bf16 planes (row-major, LINEAR).
// Same hi/lo math as the old in-loop conversion => bit-identical products.
// 8 floats per thread; grid*256*8 == B*H exactly.
// ---------------------------------------------------------------------------
__global__ __launch_bounds__(256) void convert_z(
    const float* __restrict__ z,
    unsigned short* __restrict__ zhi, unsigned short* __restrict__ zlo) {
  const size_t t = (size_t)blockIdx.x * 256 + threadIdx.x;
  const float* src = z + t * 8;
  float x[8];
  *(float4*)&x[0] = *(const float4*)src;
  *(float4*)&x[4] = *(const float4*)(src + 4);
  unsigned hv[4], lv[4];
  #pragma unroll
  for (int q = 0; q < 4; ++q) {
    unsigned short h0 = f2bf_rne(x[2 * q]), h1 = f2bf_rne(x[2 * q + 1]);
    float r0 = x[2 * q] - bf2f(h0), r1 = x[2 * q + 1] - bf2f(h1);
    unsigned short l0 = f2bf_rne(r0), l1 = f2bf_rne(r1);
    hv[q] = (unsigned)h0 | ((unsigned)h1 << 16);
    lv[q] = (unsigned)l0 | ((unsigned)l1 << 16);
  }
  *(uint4*)(zhi + t * 8) = make_uint4(hv[0], hv[1], hv[2], hv[3]);
  *(uint4*)(zlo + t * 8) = make_uint4(lv[0], lv[1], lv[2], lv[3]);
}

// ---------------------------------------------------------------------------
// Kernel 2: fused GEMM. grid = (B/BM, 3), balanced 6 tiles per split:
//   split 0: tiles  0..5   (cat cols    0..767)  -> argmin partial 0
//   split 1: tiles  6..11  (cat cols  768..1535) -> argmin partial 1
//   split 2: tiles 12..17  (cols 1536..2047 -> argmin partial 2; 2048..2303 ptr)
// All staging (A and B, hi and lo) via global_load_lds width=16, zero VALU.
//
// LDS slot swizzle (T2, both-sides per rule #21): a BK=32 row is 4 x 16B
// slots; logical (row, slot) lives at phys slot = slot ^ ((row>>1)&3).
// global_load_lds writes linearly (lane -> phys slot lane&3), so the LANE'S
// GLOBAL SOURCE fetches logical slot (lane&3)^((lane>>3)&3); ds_read applies
// the same XOR. Consecutive 8-lane groups then hit 8 distinct bank-quads
// (2-way across wave64 = free) instead of 2 quads (8-way).
// ---------------------------------------------------------------------------
__global__ __launch_bounds__(256, 2) void main_gemm(
    const unsigned short* __restrict__ zhi,
    const unsigned short* __restrict__ zlo,
    const unsigned short* __restrict__ cat_hi,
    const unsigned short* __restrict__ cat_lo,
    const float* __restrict__ normE,
    const float* __restrict__ bias,
    const int* __restrict__ plen_p,
    float* __restrict__ pmin, int* __restrict__ pidx,
    float* __restrict__ out_logits) {
  __shared__ unsigned short Ahi[BM * BK], Alo[BM * BK];
  __shared__ unsigned short Bhi[BN * BK], Blo[BN * BK];
  __shared__ float red_v[2][BM];
  __shared__ int   red_i[2][BM];

  const int tid = threadIdx.x;
  const int wave = tid >> 6, lane = tid & 63;
  const int wm = wave >> 1, wn = wave & 1;   // 2x2 wave grid, each 64x64
  const int bx = blockIdx.x, split = blockIdx.y;
  const int b0 = bx * BM;
  const int lrow = lane & 15, lk = lane >> 4;
  // read-side swizzled k-offset (shorts); row-dependence reduces to lrow
  const int csw = ((lk ^ ((lrow >> 1) & 3)) << 3);

  // staging mapping: seg = wave*2+s covers 16 rows; lane -> row seg*16+(lane>>2),
  // phys slot lane&3; fetch logical slot (lane&3)^((row>>1)&3) = (lane&3)^((lane>>3)&3)
  const int srow = lane >> 2;
  const int scol = (((lane & 3) ^ ((lane >> 3) & 3)) << 3);  // shorts

  float minv[16];
  int   mini[16];
  #pragma unroll
  for (int s = 0; s < 16; ++s) { minv[s] = 3.4e38f; mini[s] = 0; }

  // A-panel (z) source pointers: invariant across tiles
  const unsigned short* pa_hi[2];
  const unsigned short* pa_lo[2];
  #pragma unroll
  for (int s = 0; s < 2; ++s) {
    const int seg = wave * 2 + s;
    const size_t off = (size_t)(b0 + seg * 16 + srow) * H_SZ + scol;
    pa_hi[s] = zhi + off;
    pa_lo[s] = zlo + off;
  }

  const int t0 = split * TPS;
  for (int tt = t0; tt < t0 + TPS; ++tt) {
    const int n0 = tt * BN;   // cat row base for this tile
    const unsigned short* pb_hi[2];
    const unsigned short* pb_lo[2];
    #pragma unroll
    for (int s = 0; s < 2; ++s) {
      const int seg = wave * 2 + s;
      const size_t off = (size_t)(n0 + seg * 16 + srow) * H_SZ + scol;
      pb_hi[s] = cat_hi + off;
      pb_lo[s] = cat_lo + off;
    }

    floatx4 acc[4][4];
    #pragma unroll
    for (int i = 0; i < 4; ++i)
      #pragma unroll
      for (int j = 0; j < 4; ++j) acc[i][j] = (floatx4){0.f, 0.f, 0.f, 0.f};

    for (int kk = 0; kk < H_SZ; kk += BK) {
      // ---- stage A and B (hi/lo) via global_load_lds width=16, no VALU ----
      #pragma unroll
      for (int s = 0; s < 2; ++s) {
        const int seg = wave * 2 + s;          // 8 segments of 16 rows
        load_lds16(pa_hi[s] + kk, &Ahi[seg * 512]);
        load_lds16(pa_lo[s] + kk, &Alo[seg * 512]);
        load_lds16(pb_hi[s] + kk, &Bhi[seg * 512]);
        load_lds16(pb_lo[s] + kk, &Blo[seg * 512]);
      }
      __syncthreads();

      // ---- fragments (swizzled ds_read_b128) + MFMA (3 products) ----
      bf16x8 ah[4], al[4], bh[4], bl[4];
      #pragma unroll
      for (int i = 0; i < 4; ++i) {
        const int r = (wm * 64 + i * 16 + lrow) * BK + csw;
        ah[i] = *(const bf16x8*)&Ahi[r];
        al[i] = *(const bf16x8*)&Alo[r];
      }
      #pragma unroll
      for (int j = 0; j < 4; ++j) {
        const int r = (wn * 64 + j * 16 + lrow) * BK + csw;
        bh[j] = *(const bf16x8*)&Bhi[r];
        bl[j] = *(const bf16x8*)&Blo[r];
      }
      #pragma unroll
      for (int i = 0; i < 4; ++i)
        #pragma unroll
        for (int j = 0; j < 4; ++j) {
          acc[i][j] = __builtin_amdgcn_mfma_f32_16x16x32_bf16(ah[i], bh[j], acc[i][j], 0, 0, 0);
          acc[i][j] = __builtin_amdgcn_mfma_f32_16x16x32_bf16(ah[i], bl[j], acc[i][j], 0, 0, 0);
          acc[i][j] = __builtin_amdgcn_mfma_f32_16x16x32_bf16(al[i], bh[j], acc[i][j], 0, 0, 0);
        }
      __syncthreads();
    }

    // ---- per-tile epilogue ----
    if (tt < 16) {
      #pragma unroll
      for (int j = 0; j < 4; ++j) {
        const int k = n0 + wn * 64 + j * 16 + lrow;
        const float nE = normE[k];
        const bool valid = (k < K_SZ);
        #pragma unroll
        for (int i = 0; i < 4; ++i)
          #pragma unroll
          for (int r = 0; r < 4; ++r) {
            float v = nE - 2.0f * acc[i][j][r];
            if (!valid) v = 3.4e38f;
            const int s = i * 4 + r;
            if (v < minv[s]) { minv[s] = v; mini[s] = k; }  // ascending k => first-min
          }
      }
    } else {
      const int plen = *plen_p;
      #pragma unroll
      for (int j = 0; j < 4; ++j) {
        const int c = (n0 - KPAD) + wn * 64 + j * 16 + lrow;   // 0..255
        const float bv = bias[c];
        const bool masked = ((c & 127) >= plen);
        #pragma unroll
        for (int i = 0; i < 4; ++i) {
          const int growbase = b0 + wm * 64 + i * 16 + lk * 4;
          #pragma unroll
          for (int r = 0; r < 4; ++r) {
            // Sentinel must stay finite in bf16 (see MASK_NEG note).
            const float val = masked ? -MASK_NEG : (acc[i][j][r] + bv);
            out_logits[(size_t)(growbase + r) * NPTR_COLS + c] = val;
          }
        }
      }
    }
  }

  // ---- cross-lane / cross-wave argmin reduce (all 3 splits have partials) ----
  #pragma unroll
  for (int s = 0; s < 16; ++s) {
    float v = minv[s]; int id = mini[s];
    #pragma unroll
    for (int m = 1; m < 16; m <<= 1) {
      const float ov = __shfl_xor(v, m);
      const int   oid = __shfl_xor(id, m);
      if (ov < v || (ov == v && oid < id)) { v = ov; id = oid; }
    }
    if (lrow == 0) {
      const int row_local = wm * 64 + (s >> 2) * 16 + lk * 4 + (s & 3);
      red_v[wn][row_local] = v;
      red_i[wn][row_local] = id;
    }
  }
  __syncthreads();
  if (tid < BM) {
    const float v0 = red_v[0][tid], v1 = red_v[1][tid];
    float v; int id;
    if (v1 < v0) { v = v1; id = red_i[1][tid]; }
    else         { v = v0; id = red_i[0][tid]; }   // tie -> lower k (wn=0 side)
    pmin[(size_t)split * B_SZ + b0 + tid] = v;
    pidx[(size_t)split * B_SZ + b0 + tid] = id;
  }
}

// ---------------------------------------------------------------------------
// Kernel 3: merge 3 K-split partials, gather emb[idx], op_state = z + (e - z)
// ---------------------------------------------------------------------------
__global__ __launch_bounds__(256) void merge_gather(
    const float* __restrict__ z, const float* __restrict__ emb,
    const float* __restrict__ pmin, const int* __restrict__ pidx,
    float* __restrict__ out0) {
  const int row = blockIdx.x;
  float v = pmin[row];
  int  id = pidx[row];
  const float v1 = pmin[B_SZ + row];
  if (v1 < v) { v = v1; id = pidx[B_SZ + row]; }
  const float v2 = pmin[2 * (size_t)B_SZ + row];
  if (v2 < v) { v = v2; id = pidx[2 * (size_t)B_SZ + row]; }
  const float4* e4 = (const float4*)(emb + (size_t)id * H_SZ);
  const float4* z4 = (const float4*)(z + (size_t)row * H_SZ);
  float4* o4 = (float4*)(out0 + (size_t)row * H_SZ);
  const int t = threadIdx.x;
  if (t < H_SZ / 4) {  // 224
    const float4 zz = z4[t], ee = e4[t];
    float4 r;
    r.x = zz.x + (ee.x - zz.x);
    r.y = zz.y + (ee.y - zz.y);
    r.z = zz.z + (ee.z - zz.z);
    r.w = zz.w + (ee.w - zz.w);
    o4[t] = r;
  }
}

extern "C" void kernel_launch(void* const* d_in, const int* in_sizes, int n_in,
                              void* d_out, int out_size, void* d_ws, size_t ws_size,
                              hipStream_t stream) {
  const float* z    = (const float*)d_in[0];
  const float* emb  = (const float*)d_in[1];
  const float* W    = (const float*)d_in[2];
  const float* bias = (const float*)d_in[3];
  const int*   plen = (const int*)d_in[4];
  float* out = (float*)d_out;

  char* ws = (char*)d_ws;
  // cat_hi: 2304*896*2 = 4,128,768 B ; cat_lo same ; normE 8 KB ; 3-way partials
  unsigned short* cat_hi = (unsigned short*)(ws);
  unsigned short* cat_lo = (unsigned short*)(ws + 4128768);
  float* normE = (float*)(ws + 8257536);
  float* pmin  = (float*)(ws + 8265728);   // 3 * 32768 * 4 = 393,216 B
  int*   pidx  = (int*)(ws + 8658944);     // 3 * 32768 * 4 = 393,216 B

  // z hi/lo bf16 planes staged IN THE OUTPUT BUFFER's op_state region
  // (exactly B*H*4 bytes). main_gemm consumes them fully before merge_gather
  // overwrites the region with op_state (stream order guarantees this).
  unsigned short* zhi = (unsigned short*)out;
  unsigned short* zlo = zhi + (size_t)B_SZ * H_SZ;
  float* out_logits = out + (size_t)B_SZ * H_SZ;   // second output, [B,2,128]

  convert_kernel<<<dim3(NCAT), dim3(256), 0, stream>>>(emb, W, cat_hi, cat_lo, normE);
  convert_z<<<dim3(B_SZ * H_SZ / (256 * 8)), dim3(256), 0, stream>>>(z, zhi, zlo);
  main_gemm<<<dim3(B_SZ / BM, 3), dim3(256), 0, stream>>>(
      zhi, zlo, cat_hi, cat_lo, normE, bias, plen, pmin, pidx, out_logits);
  merge_gather<<<dim3(B_SZ), dim3(256), 0, stream>>>(z, emb, pmin, pidx, out);
}

// Round 2
// 668.511 us; speedup vs baseline: 1.1142x; 1.1142x over previous
//
#include <hip/hip_runtime.h>
#include <hip/hip_bf16.h>
#include <cstdint>
#include <cstddef>

#define B_SZ 32768
#define H_SZ 896
#define K_SZ 2000
#define KPAD 2048
#define NPTR_COLS 256
#define NCAT 2304   /* KPAD + NPTR_COLS */
#define BM 256
#define BN 256
#define BK 32
#define NKS (H_SZ / BK)   /* 28 K-steps */
#define NT_ARG 8          /* n-tiles 0..7 are argmin tiles; tile 8 is ptr */

typedef float floatx4 __attribute__((ext_vector_type(4)));
typedef __bf16 bf16x8 __attribute__((ext_vector_type(8)));

// Masked-logit sentinel: must stay FINITE after bf16 RNE rounding (harness
// compares through bf16; -3.4e38 rounds to -inf there and produced nan).
#define MASK_NEG 1.0e30f

__device__ inline unsigned short f2bf_rne(float x) {
  unsigned u = __builtin_bit_cast(unsigned, x);
  unsigned r = u + 0x7fffu + ((u >> 16) & 1u);
  return (unsigned short)(r >> 16);
}
__device__ inline float bf2f(unsigned short b) {
  unsigned u = ((unsigned)b) << 16;
  return __builtin_bit_cast(float, u);
}

typedef __attribute__((address_space(1))) void GV;
typedef __attribute__((address_space(3))) void LV;
__device__ inline void load_lds16(const void* gsrc, void* ldst) {
  __builtin_amdgcn_global_load_lds((GV*)gsrc, (LV*)ldst, 16, 0, 0);
}

// ---------------------------------------------------------------------------
// Kernel 1 (fused): blocks [0, NCAT) build cat_hi/cat_lo bf16 split of
// [emb(2000); zeros(48); W(256)] rows x 896 plus normE[k]; blocks >= NCAT
// convert z -> zhi/zlo planes (8 floats per thread). Same hi/lo math
// everywhere => bit-identical MFMA inputs vs the verified kernel.
// ---------------------------------------------------------------------------
__global__ __launch_bounds__(256) void convert_all(
    const float* __restrict__ emb, const float* __restrict__ W,
    const float* __restrict__ z,
    unsigned short* __restrict__ cat_hi, unsigned short* __restrict__ cat_lo,
    float* __restrict__ normE,
    unsigned short* __restrict__ zhi, unsigned short* __restrict__ zlo) {
  const int bid = blockIdx.x;
  const int tid = threadIdx.x;
  if (bid < NCAT) {
    const int row = bid;
    const float* src = nullptr;
    bool zero = false;
    if (row < K_SZ)       src = emb + (size_t)row * H_SZ;
    else if (row < KPAD)  zero = true;
    else                  src = W + (size_t)(row - KPAD) * H_SZ;

    float ss = 0.f;
    for (int c = tid; c < H_SZ; c += 256) {
      float x = zero ? 0.f : src[c];
      unsigned short hb = f2bf_rne(x);
      float hf = bf2f(hb);
      unsigned short lb = f2bf_rne(x - hf);
      cat_hi[(size_t)row * H_SZ + c] = hb;
      cat_lo[(size_t)row * H_SZ + c] = lb;
      ss += x * x;
    }
    #pragma unroll
    for (int off = 32; off > 0; off >>= 1) ss += __shfl_down(ss, off);
    __shared__ float wsum[4];
    const int wave = tid >> 6, lane = tid & 63;
    if (lane == 0) wsum[wave] = ss;
    __syncthreads();
    if (tid == 0 && row < KPAD) normE[row] = wsum[0] + wsum[1] + wsum[2] + wsum[3];
  } else {
    const size_t t = (size_t)(bid - NCAT) * 256 + tid;
    const float* src = z + t * 8;
    float x[8];
    *(float4*)&x[0] = *(const float4*)src;
    *(float4*)&x[4] = *(const float4*)(src + 4);
    unsigned hv[4], lv[4];
    #pragma unroll
    for (int q = 0; q < 4; ++q) {
      unsigned short h0 = f2bf_rne(x[2 * q]), h1 = f2bf_rne(x[2 * q + 1]);
      float r0 = x[2 * q] - bf2f(h0), r1 = x[2 * q + 1] - bf2f(h1);
      unsigned short l0 = f2bf_rne(r0), l1 = f2bf_rne(r1);
      hv[q] = (unsigned)h0 | ((unsigned)h1 << 16);
      lv[q] = (unsigned)l0 | ((unsigned)l1 << 16);
    }
    *(uint4*)(zhi + t * 8) = make_uint4(hv[0], hv[1], hv[2], hv[3]);
    *(uint4*)(zlo + t * 8) = make_uint4(lv[0], lv[1], lv[2], lv[3]);
  }
}

// ---------------------------------------------------------------------------
// Kernel 2: 256x256-tile 8-phase fused GEMM. grid = (B/256, 9).
//   n-tile 0..7: cat cols nt*256.. -> per-row argmin partial nt
//   n-tile 8   : ptr logits (+bias, prompt-len mask)
// s = z . cat_row as bf16x3 (hi*hi + hi*lo + lo*hi), fp32 acc (same order as
// the verified kernel => bit-identical). dist proxy v = normE[k] - 2*s.
//
// Schedule (T3+T4+T5 per 8-phase template): per K-step (BK=32) 4 phases,
// each { ds_read quadrant frags ; issue prefetch DMA ; s_barrier ;
// setprio(1) 24xMFMA setprio(0) ; s_barrier }. Prefetch of K-step k+1 is
// issued in phases 1-2 of k and drained by ONE vmcnt(0) at the end of
// phase 4 (>=2 phases of latency cover) -- raw s_barrier keeps the DMA in
// flight across barriers (no __syncthreads drain in the main loop).
//
// LDS slot swizzle (both-sides, proven 0-conflict in prior round): logical
// 16B slot s of row r lives at phys slot s ^ ((r>>1)&3); DMA writes
// linearly so the lane's GLOBAL source fetches logical slot
// (lane&3)^((lane>>3)&3); ds_read applies the same XOR (csw).
// ---------------------------------------------------------------------------
__global__ __launch_bounds__(512, 2) void main_gemm(
    const unsigned short* __restrict__ zhi,
    const unsigned short* __restrict__ zlo,
    const unsigned short* __restrict__ cat_hi,
    const unsigned short* __restrict__ cat_lo,
    const float* __restrict__ normE,
    const float* __restrict__ bias,
    const int* __restrict__ plen_p,
    float* __restrict__ pmin, int* __restrict__ pidx,
    float* __restrict__ out_logits) {
  // 2 bufs x 2 planes x 256x32 ushort = 64 KB each for A and B -> 128 KB
  __shared__ unsigned short ldsA[2][2][BM * BK];
  __shared__ unsigned short ldsB[2][2][BN * BK];
  __shared__ float red_v[4][BM];
  __shared__ int   red_i[4][BM];

  const int tid = threadIdx.x;
  const int wave = tid >> 6, lane = tid & 63;
  const int wm = wave >> 2, wn = wave & 3;     // 2 x 4 wave grid; wave out 128x64
  const int m0 = blockIdx.x * BM;
  const int nt = blockIdx.y;
  const int n0 = nt * BN;
  const int lrow = lane & 15, lk = lane >> 4;
  const int csw = ((lk ^ ((lrow >> 1) & 3)) << 3);   // swizzled k-offset (shorts)

  // staging lane map: lane -> row seg*16+(lane>>2), phys slot lane&3;
  // source fetches logical slot (lane&3)^((lane>>3)&3)
  const int srow = lane >> 2;
  const int scol = (((lane & 3) ^ ((lane >> 3) & 3)) << 3);  // shorts

  // global source offsets (shorts) for this wave's two 16-row segments/array
  size_t offA[2], offB[2];
  #pragma unroll
  for (int s = 0; s < 2; ++s) {
    const int seg = wave * 2 + s;            // 0..15
    offA[s] = (size_t)(m0 + seg * 16 + srow) * H_SZ + scol;
    offB[s] = (size_t)(n0 + seg * 16 + srow) * H_SZ + scol;
  }

  auto STAGE = [&](int b, int s, int kk) {
    const int seg = wave * 2 + s;
    load_lds16(zhi    + offA[s] + kk, &ldsA[b][0][seg * 512]);
    load_lds16(zlo    + offA[s] + kk, &ldsA[b][1][seg * 512]);
    load_lds16(cat_hi + offB[s] + kk, &ldsB[b][0][seg * 512]);
    load_lds16(cat_lo + offB[s] + kk, &ldsB[b][1][seg * 512]);
  };

  floatx4 acc[8][4];
  #pragma unroll
  for (int i = 0; i < 8; ++i)
    #pragma unroll
    for (int j = 0; j < 4; ++j) acc[i][j] = (floatx4){0.f, 0.f, 0.f, 0.f};

  bf16x8 ah[4], al[4], b0h[2], b0l[2], b1h[2], b1l[2];

  auto RD_A = [&](int b, int mhalf) {
    #pragma unroll
    for (int i = 0; i < 4; ++i) {
      const int r = (wm * 128 + (mhalf * 4 + i) * 16 + lrow) * BK + csw;
      ah[i] = *(const bf16x8*)&ldsA[b][0][r];
      al[i] = *(const bf16x8*)&ldsA[b][1][r];
    }
  };
  auto RD_B0 = [&](int b, int nhalf) {
    #pragma unroll
    for (int j = 0; j < 2; ++j) {
      const int r = (wn * 64 + (nhalf * 2 + j) * 16 + lrow) * BK + csw;
      b0h[j] = *(const bf16x8*)&ldsB[b][0][r];
      b0l[j] = *(const bf16x8*)&ldsB[b][1][r];
    }
  };
  auto RD_B1 = [&](int b, int nhalf) {
    #pragma unroll
    for (int j = 0; j < 2; ++j) {
      const int r = (wn * 64 + (nhalf * 2 + j) * 16 + lrow) * BK + csw;
      b1h[j] = *(const bf16x8*)&ldsB[b][0][r];
      b1l[j] = *(const bf16x8*)&ldsB[b][1][r];
    }
  };

  // prologue: stage K-step 0 into buf0, drain, sync
  STAGE(0, 0, 0);
  STAGE(0, 1, 0);
  asm volatile("s_waitcnt vmcnt(0)" ::: "memory");
  __builtin_amdgcn_s_barrier();

  for (int ks = 0; ks < NKS; ++ks) {
    const int cur = ks & 1, nxt = cur ^ 1;
    const int kk1 = (ks + 1) * BK;
    const bool pf = (ks + 1 < NKS);

    // ---- phase 1: quadrant (mhalf0, nhalf0) ----
    RD_A(cur, 0);
    RD_B0(cur, 0);
    if (pf) STAGE(nxt, 0, kk1);
    __builtin_amdgcn_s_barrier();
    __builtin_amdgcn_s_setprio(1);
    #pragma unroll
    for (int i = 0; i < 4; ++i)
      #pragma unroll
      for (int j = 0; j < 2; ++j) {
        floatx4 c = acc[i][j];
        c = __builtin_amdgcn_mfma_f32_16x16x32_bf16(ah[i], b0h[j], c, 0, 0, 0);
        c = __builtin_amdgcn_mfma_f32_16x16x32_bf16(ah[i], b0l[j], c, 0, 0, 0);
        c = __builtin_amdgcn_mfma_f32_16x16x32_bf16(al[i], b0h[j], c, 0, 0, 0);
        acc[i][j] = c;
      }
    __builtin_amdgcn_s_setprio(0);
    __builtin_amdgcn_s_barrier();

    // ---- phase 2: quadrant (mhalf0, nhalf1) -- A held ----
    RD_B1(cur, 1);
    if (pf) STAGE(nxt, 1, kk1);
    __builtin_amdgcn_s_barrier();
    __builtin_amdgcn_s_setprio(1);
    #pragma unroll
    for (int i = 0; i < 4; ++i)
      #pragma unroll
      for (int j = 0; j < 2; ++j) {
        floatx4 c = acc[i][2 + j];
        c = __builtin_amdgcn_mfma_f32_16x16x32_bf16(ah[i], b1h[j], c, 0, 0, 0);
        c = __builtin_amdgcn_mfma_f32_16x16x32_bf16(ah[i], b1l[j], c, 0, 0, 0);
        c = __builtin_amdgcn_mfma_f32_16x16x32_bf16(al[i], b1h[j], c, 0, 0, 0);
        acc[i][2 + j] = c;
      }
    __builtin_amdgcn_s_setprio(0);
    __builtin_amdgcn_s_barrier();

    // ---- phase 3: quadrant (mhalf1, nhalf1) -- B1 held ----
    RD_A(cur, 1);
    __builtin_amdgcn_s_barrier();
    __builtin_amdgcn_s_setprio(1);
    #pragma unroll
    for (int i = 0; i < 4; ++i)
      #pragma unroll
      for (int j = 0; j < 2; ++j) {
        floatx4 c = acc[4 + i][2 + j];
        c = __builtin_amdgcn_mfma_f32_16x16x32_bf16(ah[i], b1h[j], c, 0, 0, 0);
        c = __builtin_amdgcn_mfma_f32_16x16x32_bf16(ah[i], b1l[j], c, 0, 0, 0);
        c = __builtin_amdgcn_mfma_f32_16x16x32_bf16(al[i], b1h[j], c, 0, 0, 0);
        acc[4 + i][2 + j] = c;
      }
    __builtin_amdgcn_s_setprio(0);
    __builtin_amdgcn_s_barrier();

    // ---- phase 4: quadrant (mhalf1, nhalf0) -- A held, B0 re-read ----
    RD_B0(cur, 0);
    __builtin_amdgcn_s_barrier();
    __builtin_amdgcn_s_setprio(1);
    #pragma unroll
    for (int i = 0; i < 4; ++i)
      #pragma unroll
      for (int j = 0; j < 2; ++j) {
        floatx4 c = acc[4 + i][j];
        c = __builtin_amdgcn_mfma_f32_16x16x32_bf16(ah[i], b0h[j], c, 0, 0, 0);
        c = __builtin_amdgcn_mfma_f32_16x16x32_bf16(ah[i], b0l[j], c, 0, 0, 0);
        c = __builtin_amdgcn_mfma_f32_16x16x32_bf16(al[i], b0h[j], c, 0, 0, 0);
        acc[4 + i][j] = c;
      }
    __builtin_amdgcn_s_setprio(0);
    if (pf) { asm volatile("s_waitcnt vmcnt(0)" ::: "memory"); }
    __builtin_amdgcn_s_barrier();
    __builtin_amdgcn_sched_barrier(0);   // pin: no cross-iteration hoist
  }

  // ------------------------------ epilogue ------------------------------
  if (nt < NT_ARG) {
    float nE[4]; bool valid[4]; int kcol[4];
    #pragma unroll
    for (int nj = 0; nj < 4; ++nj) {
      kcol[nj] = n0 + wn * 64 + nj * 16 + lrow;
      valid[nj] = (kcol[nj] < K_SZ);
      nE[nj] = normE[kcol[nj]];
    }
    #pragma unroll
    for (int mi = 0; mi < 8; ++mi) {
      #pragma unroll
      for (int r = 0; r < 4; ++r) {
        float v = 3.4e38f; int id = kcol[0];
        #pragma unroll
        for (int nj = 0; nj < 4; ++nj) {
          const float vv = valid[nj] ? (nE[nj] - 2.0f * acc[mi][nj][r]) : 3.4e38f;
          if (vv < v) { v = vv; id = kcol[nj]; }   // nj ascending => lowest k on ties
        }
        #pragma unroll
        for (int m = 1; m < 16; m <<= 1) {
          const float ov = __shfl_xor(v, m);
          const int   oid = __shfl_xor(id, m);
          if (ov < v || (ov == v && oid < id)) { v = ov; id = oid; }
        }
        if (lrow == 0) {
          const int row_local = wm * 128 + mi * 16 + lk * 4 + r;
          red_v[wn][row_local] = v;
          red_i[wn][row_local] = id;
        }
      }
    }
    __syncthreads();
    if (tid < BM) {
      float v = red_v[0][tid]; int id = red_i[0][tid];
      #pragma unroll
      for (int w = 1; w < 4; ++w) {        // wn ascending = k ascending; strict <
        const float vw = red_v[w][tid];
        if (vw < v) { v = vw; id = red_i[w][tid]; }
      }
      pmin[(size_t)nt * B_SZ + m0 + tid] = v;
      pidx[(size_t)nt * B_SZ + m0 + tid] = id;
    }
  } else {
    const int plen = *plen_p;
    #pragma unroll
    for (int nj = 0; nj < 4; ++nj) {
      const int c = wn * 64 + nj * 16 + lrow;       // 0..255
      const float bv = bias[c];
      const bool masked = ((c & 127) >= plen);
      #pragma unroll
      for (int mi = 0; mi < 8; ++mi) {
        const int growbase = m0 + wm * 128 + mi * 16 + lk * 4;
        #pragma unroll
        for (int r = 0; r < 4; ++r) {
          // Sentinel must stay finite in bf16 (see MASK_NEG note).
          const float val = masked ? -MASK_NEG : (acc[mi][nj][r] + bv);
          out_logits[(size_t)(growbase + r) * NPTR_COLS + c] = val;
        }
      }
    }
  }
}

// ---------------------------------------------------------------------------
// Kernel 3: merge 8 K-split partials, gather emb[idx], op_state = z + (e - z)
// ---------------------------------------------------------------------------
__global__ __launch_bounds__(256) void merge_gather(
    const float* __restrict__ z, const float* __restrict__ emb,
    const float* __restrict__ pmin, const int* __restrict__ pidx,
    float* __restrict__ out0) {
  const int row = blockIdx.x;
  float v = pmin[row];
  int  id = pidx[row];
  #pragma unroll
  for (int t = 1; t < NT_ARG; ++t) {       // ascending k-ranges; strict <
    const float vt = pmin[(size_t)t * B_SZ + row];
    if (vt < v) { v = vt; id = pidx[(size_t)t * B_SZ + row]; }
  }
  const float4* e4 = (const float4*)(emb + (size_t)id * H_SZ);
  const float4* z4 = (const float4*)(z + (size_t)row * H_SZ);
  float4* o4 = (float4*)(out0 + (size_t)row * H_SZ);
  const int t = threadIdx.x;
  if (t < H_SZ / 4) {  // 224
    const float4 zz = z4[t], ee = e4[t];
    float4 r;
    r.x = zz.x + (ee.x - zz.x);
    r.y = zz.y + (ee.y - zz.y);
    r.z = zz.z + (ee.z - zz.z);
    r.w = zz.w + (ee.w - zz.w);
    o4[t] = r;
  }
}

extern "C" void kernel_launch(void* const* d_in, const int* in_sizes, int n_in,
                              void* d_out, int out_size, void* d_ws, size_t ws_size,
                              hipStream_t stream) {
  const float* z    = (const float*)d_in[0];
  const float* emb  = (const float*)d_in[1];
  const float* W    = (const float*)d_in[2];
  const float* bias = (const float*)d_in[3];
  const int*   plen = (const int*)d_in[4];
  float* out = (float*)d_out;

  char* ws = (char*)d_ws;
  // cat_hi: 2304*896*2 = 4,128,768 B ; cat_lo same ; normE 8 KB ; 8-way partials
  unsigned short* cat_hi = (unsigned short*)(ws);
  unsigned short* cat_lo = (unsigned short*)(ws + 4128768);
  float* normE = (float*)(ws + 8257536);
  float* pmin  = (float*)(ws + 8265728);   // 8 * 32768 * 4 = 1,048,576 B
  int*   pidx  = (int*)(ws + 9314304);     // 8 * 32768 * 4 = 1,048,576 B

  // z hi/lo bf16 planes staged IN THE OUTPUT BUFFER's op_state region
  // (exactly B*H*4 bytes). main_gemm consumes them fully before merge_gather
  // overwrites the region with op_state (stream order guarantees this).
  unsigned short* zhi = (unsigned short*)out;
  unsigned short* zlo = zhi + (size_t)B_SZ * H_SZ;
  float* out_logits = out + (size_t)B_SZ * H_SZ;   // second output, [B,2,128]

  // fused conversion: 2304 cat blocks + 14336 z blocks (32768*896/2048)
  convert_all<<<dim3(NCAT + B_SZ * H_SZ / 2048), dim3(256), 0, stream>>>(
      emb, W, z, cat_hi, cat_lo, normE, zhi, zlo);
  main_gemm<<<dim3(B_SZ / BM, 9), dim3(512), 0, stream>>>(
      zhi, zlo, cat_hi, cat_lo, normE, bias, plen, pmin, pidx, out_logits);
  merge_gather<<<dim3(B_SZ), dim3(256), 0, stream>>>(z, emb, pmin, pidx, out);
}